// Round 1
// baseline (144.478 us; speedup 1.0000x reference)
//
#include <hip/hip_runtime.h>
#include <hip/hip_bf16.h>
#include <math.h>

#define B_ 8
#define N_ 256
#define H_ 128

__device__ __forceinline__ float silu_fast(float x) {
    // x * sigmoid(x) = x / (1 + e^-x); native exp + rcp (2 ULP-ish, fine vs 0.114 threshold)
    float e = __expf(-x);
    return x * __builtin_amdgcn_rcpf(1.0f + e);
}

// ---------------------------------------------------------------------------
// K1: P[n][c] = sum_k node[n][k]*We1[k][c] + be1[c]   (node_i half, bias folded)
//     Q[n][c] = sum_k node[n][k]*We1[128+k][c]        (node_j half)
// grid = 2048/8 = 256 blocks, 256 threads. thread: half=t>>7, i_loc=(t>>4)&7, 8 channels.
// ---------------------------------------------------------------------------
__global__ __launch_bounds__(256) void k1_pq(
    const float* __restrict__ node, const float* __restrict__ We1,
    const float* __restrict__ be1, float* __restrict__ P, float* __restrict__ Q)
{
    __shared__ float nls[8][132];   // stride 132: broadcast reads hit distinct banks
    const int t = threadIdx.x;
    const int base_node = blockIdx.x * 8;
    {
        int idx = t * 4;
        int r = idx >> 7;
        int col = idx & 127;
        *(float4*)(&nls[r][col]) = *(const float4*)(node + (base_node + r) * H_ + col);
    }
    __syncthreads();
    const int half = t >> 7;          // 0 -> P, 1 -> Q
    const int il   = (t >> 4) & 7;
    const int c0   = (t & 15) * 8;
    const float* W = We1 + half * 128 * H_;
    float4 a0 = make_float4(0.f,0.f,0.f,0.f), a1 = make_float4(0.f,0.f,0.f,0.f);
    #pragma unroll 4
    for (int k = 0; k < 128; ++k) {
        float nv = nls[il][k];
        float4 w0 = *(const float4*)(W + k * H_ + c0);
        float4 w1 = *(const float4*)(W + k * H_ + c0 + 4);
        a0.x = fmaf(nv, w0.x, a0.x); a0.y = fmaf(nv, w0.y, a0.y);
        a0.z = fmaf(nv, w0.z, a0.z); a0.w = fmaf(nv, w0.w, a0.w);
        a1.x = fmaf(nv, w1.x, a1.x); a1.y = fmaf(nv, w1.y, a1.y);
        a1.z = fmaf(nv, w1.z, a1.z); a1.w = fmaf(nv, w1.w, a1.w);
    }
    if (!half) {
        float4 b0 = *(const float4*)(be1 + c0);
        float4 b1 = *(const float4*)(be1 + c0 + 4);
        a0.x += b0.x; a0.y += b0.y; a0.z += b0.z; a0.w += b0.w;
        a1.x += b1.x; a1.y += b1.y; a1.z += b1.z; a1.w += b1.w;
    }
    float* outp = half ? Q : P;
    *(float4*)(outp + (base_node + il) * H_ + c0)     = a0;
    *(float4*)(outp + (base_node + il) * H_ + c0 + 4) = a1;
}

// ---------------------------------------------------------------------------
// K2: S[i][c] = sum_j mask_j * silu(P[i][c] + Q[j][c] + d_ij*wd[c])
// grid = 2048/4 = 512 blocks (4 nodes i per block), 256 threads (c = t&127, j-half = t>>7)
// ---------------------------------------------------------------------------
__global__ __launch_bounds__(256) void k2_edge(
    const float* __restrict__ P, const float* __restrict__ Q,
    const float* __restrict__ We1, const float* __restrict__ positions,
    const float* __restrict__ mask, float* __restrict__ S)
{
    __shared__ float dls[256][4];     // dls[j][il]: one b128 broadcast per j
    __shared__ float mls[256];
    __shared__ float part[2][4][128];
    const int t  = threadIdx.x;
    const int b  = blockIdx.x >> 6;
    const int i0 = (blockIdx.x & 63) * 4;

    mls[t] = mask[b * N_ + t];
    {
        const int il = t & 3;
        const int jb = t >> 2;
        const float* pb = positions + b * N_ * 3;
        const float pix = pb[(i0 + il) * 3 + 0];
        const float piy = pb[(i0 + il) * 3 + 1];
        const float piz = pb[(i0 + il) * 3 + 2];
        #pragma unroll
        for (int s = 0; s < 4; ++s) {
            int j = jb + 64 * s;
            float dx = pix - pb[j * 3 + 0];
            float dy = piy - pb[j * 3 + 1];
            float dz = piz - pb[j * 3 + 2];
            float sq = dx * dx + dy * dy + dz * dz;
            dls[j][il] = (sq > 0.0f) ? sqrtf(sq) : 0.0f;
        }
    }
    __syncthreads();
    const int c  = t & 127;
    const int jh = t >> 7;
    const float wdc = We1[256 * H_ + c];            // dist row of We1
    const float base0 = P[(b * N_ + i0 + 0) * H_ + c];
    const float base1 = P[(b * N_ + i0 + 1) * H_ + c];
    const float base2 = P[(b * N_ + i0 + 2) * H_ + c];
    const float base3 = P[(b * N_ + i0 + 3) * H_ + c];
    float acc0 = 0.f, acc1 = 0.f, acc2 = 0.f, acc3 = 0.f;
    const float* Qb = Q + (b * N_ + jh * 128) * H_ + c;
    #pragma unroll 4
    for (int jj = 0; jj < 128; ++jj) {
        const int j = jh * 128 + jj;
        float q  = Qb[jj * H_];
        float mj = mls[j];
        float4 d4 = *(const float4*)(&dls[j][0]);
        float x0 = fmaf(d4.x, wdc, base0 + q);
        float x1 = fmaf(d4.y, wdc, base1 + q);
        float x2 = fmaf(d4.z, wdc, base2 + q);
        float x3 = fmaf(d4.w, wdc, base3 + q);
        acc0 = fmaf(silu_fast(x0), mj, acc0);
        acc1 = fmaf(silu_fast(x1), mj, acc1);
        acc2 = fmaf(silu_fast(x2), mj, acc2);
        acc3 = fmaf(silu_fast(x3), mj, acc3);
    }
    part[jh][0][c] = acc0; part[jh][1][c] = acc1;
    part[jh][2][c] = acc2; part[jh][3][c] = acc3;
    __syncthreads();
    if (t < 128) {
        #pragma unroll
        for (int il = 0; il < 4; ++il)
            S[(b * N_ + i0 + il) * H_ + t] = part[0][il][t] + part[1][il][t];
    }
}

// ---------------------------------------------------------------------------
// K3: agg = mask_i*(S@We2 + cnt*be2)/max(mask_i*cnt,1)
//     out = node + mask_i*(silu(node@Wn1a + agg@Wn1b + bn1)@Wn2 + bn2)
// grid = 2048/8 = 256 blocks (8 nodes), 256 threads (il = t>>5, 4 channels each)
// ---------------------------------------------------------------------------
__global__ __launch_bounds__(256) void k3_node(
    const float* __restrict__ node, const float* __restrict__ S,
    const float* __restrict__ mask,
    const float* __restrict__ We2, const float* __restrict__ be2,
    const float* __restrict__ Wn1, const float* __restrict__ bn1,
    const float* __restrict__ Wn2, const float* __restrict__ bn2,
    float* __restrict__ out)
{
    __shared__ float Sls[8][132], nls[8][132], als[8][132], hls[8][132];
    __shared__ float wsum[4];
    const int t  = threadIdx.x;
    const int b  = blockIdx.x >> 5;
    const int i0 = (blockIdx.x & 31) * 8;
    {
        int idx = t * 4;
        int r = idx >> 7;
        int col = idx & 127;
        *(float4*)(&Sls[r][col]) = *(const float4*)(S    + (b * N_ + i0 + r) * H_ + col);
        *(float4*)(&nls[r][col]) = *(const float4*)(node + (b * N_ + i0 + r) * H_ + col);
    }
    // cnt = sum_j mask[b][j]
    float m = mask[b * N_ + t];
    #pragma unroll
    for (int off = 32; off >= 1; off >>= 1) m += __shfl_down(m, off);
    if ((t & 63) == 0) wsum[t >> 6] = m;
    __syncthreads();
    const float cnt = wsum[0] + wsum[1] + wsum[2] + wsum[3];
    const int il = t >> 5;
    const int c0 = (t & 31) * 4;
    const float mask_i = mask[b * N_ + i0 + il];

    // phase A: agg
    float4 a = make_float4(0.f,0.f,0.f,0.f);
    #pragma unroll 4
    for (int k = 0; k < 128; ++k) {
        float s = Sls[il][k];
        float4 w = *(const float4*)(We2 + k * H_ + c0);
        a.x = fmaf(s, w.x, a.x); a.y = fmaf(s, w.y, a.y);
        a.z = fmaf(s, w.z, a.z); a.w = fmaf(s, w.w, a.w);
    }
    const float inv = mask_i * __builtin_amdgcn_rcpf(fmaxf(mask_i * cnt, 1.0f));
    float4 b2 = *(const float4*)(be2 + c0);
    float4 ag;
    ag.x = inv * fmaf(cnt, b2.x, a.x);
    ag.y = inv * fmaf(cnt, b2.y, a.y);
    ag.z = inv * fmaf(cnt, b2.z, a.z);
    ag.w = inv * fmaf(cnt, b2.w, a.w);
    *(float4*)(&als[il][c0]) = ag;
    __syncthreads();

    // phase B: hidden = silu([node, agg] @ Wn1 + bn1)
    float4 h = make_float4(0.f,0.f,0.f,0.f);
    #pragma unroll 4
    for (int k = 0; k < 128; ++k) {
        float v = nls[il][k];
        float4 w = *(const float4*)(Wn1 + k * H_ + c0);
        h.x = fmaf(v, w.x, h.x); h.y = fmaf(v, w.y, h.y);
        h.z = fmaf(v, w.z, h.z); h.w = fmaf(v, w.w, h.w);
    }
    #pragma unroll 4
    for (int k = 0; k < 128; ++k) {
        float v = als[il][k];
        float4 w = *(const float4*)(Wn1 + (128 + k) * H_ + c0);
        h.x = fmaf(v, w.x, h.x); h.y = fmaf(v, w.y, h.y);
        h.z = fmaf(v, w.z, h.z); h.w = fmaf(v, w.w, h.w);
    }
    float4 b1v = *(const float4*)(bn1 + c0);
    float4 hs;
    hs.x = silu_fast(h.x + b1v.x);
    hs.y = silu_fast(h.y + b1v.y);
    hs.z = silu_fast(h.z + b1v.z);
    hs.w = silu_fast(h.w + b1v.w);
    *(float4*)(&hls[il][c0]) = hs;
    __syncthreads();

    // phase C: out = node + mask_i * (hidden @ Wn2 + bn2)
    float4 u = make_float4(0.f,0.f,0.f,0.f);
    #pragma unroll 4
    for (int k = 0; k < 128; ++k) {
        float v = hls[il][k];
        float4 w = *(const float4*)(Wn2 + k * H_ + c0);
        u.x = fmaf(v, w.x, u.x); u.y = fmaf(v, w.y, u.y);
        u.z = fmaf(v, w.z, u.z); u.w = fmaf(v, w.w, u.w);
    }
    float4 b3 = *(const float4*)(bn2 + c0);
    float4 res;
    res.x = nls[il][c0 + 0] + mask_i * (u.x + b3.x);
    res.y = nls[il][c0 + 1] + mask_i * (u.y + b3.y);
    res.z = nls[il][c0 + 2] + mask_i * (u.z + b3.z);
    res.w = nls[il][c0 + 3] + mask_i * (u.w + b3.w);
    *(float4*)(out + (b * N_ + i0 + il) * H_ + c0) = res;
}

extern "C" void kernel_launch(void* const* d_in, const int* in_sizes, int n_in,
                              void* d_out, int out_size, void* d_ws, size_t ws_size,
                              hipStream_t stream)
{
    const float* node      = (const float*)d_in[0];
    const float* positions = (const float*)d_in[1];
    const float* mask      = (const float*)d_in[2];
    const float* We1       = (const float*)d_in[3];
    const float* be1       = (const float*)d_in[4];
    const float* We2       = (const float*)d_in[5];
    const float* be2       = (const float*)d_in[6];
    const float* Wn1       = (const float*)d_in[7];
    const float* bn1       = (const float*)d_in[8];
    const float* Wn2       = (const float*)d_in[9];
    const float* bn2       = (const float*)d_in[10];
    float* out = (float*)d_out;

    float* P = (float*)d_ws;                 // [2048][128]
    float* Q = P + B_ * N_ * H_;             // [2048][128]
    float* S = Q + B_ * N_ * H_;             // [2048][128]  (needs 3 MB of ws)

    k1_pq  <<<B_ * N_ / 8, 256, 0, stream>>>(node, We1, be1, P, Q);
    k2_edge<<<B_ * N_ / 4, 256, 0, stream>>>(P, Q, We1, positions, mask, S);
    k3_node<<<B_ * N_ / 8, 256, 0, stream>>>(node, S, mask, We2, be2, Wn1, bn1, Wn2, bn2, out);
}